// Round 1
// baseline (127.363 us; speedup 1.0000x reference)
//
#include <hip/hip_runtime.h>
#include <hip/hip_bf16.h>

// Sizes fixed by the problem
// B=16, N=2048, DIM_X=512, DIM_E=64, F=576 (=512+64)

typedef __attribute__((ext_vector_type(8))) short s16x8;
typedef __attribute__((ext_vector_type(4))) short s16x4;
typedef __attribute__((ext_vector_type(4))) float f32x4;

#define BM 128
#define BN 64
#define BK 64
#define KPAD 8   // bf16 elements of row padding -> 144B row stride, 2-way-free banks

__device__ __forceinline__ unsigned short f2bf(float f) {
  union { float f; unsigned u; } v; v.f = f;
  unsigned r = v.u + 0x7fff + ((v.u >> 16) & 1);   // RNE
  return (unsigned short)(r >> 16);
}

// ---------------------------------------------------------------------------
// NT-GEMM: C[i][j] = sum_k A[i][k] * B[j][k], A: M x K row-major, B: N x K
// row-major, C: M x N. bf16 inputs, fp32 accumulate, bf16 or f32 out.
// Tile 128x64, BK=64. 256 threads = 4 waves in 2x2, each wave 64x32.
// M % 128 == 0, N % 64 == 0, K % 64 == 0 guaranteed by caller.
// ---------------------------------------------------------------------------
template<int OUT_F32>
__global__ __launch_bounds__(256) void gemm_nt(
    const unsigned short* __restrict__ A, long sAb, int lda,
    const unsigned short* __restrict__ B, long sBb, int ldb,
    void* __restrict__ Cptr, long sCb, int ldc,
    int K)
{
  __shared__ unsigned short As[BM][BK + KPAD];
  __shared__ unsigned short Bs[BN][BK + KPAD];

  const int bz = blockIdx.z;
  A += (long)bz * sAb;
  B += (long)bz * sBb;
  const int m0 = blockIdx.x * BM;
  const int n0 = blockIdx.y * BN;

  const int tid  = threadIdx.x;
  const int lane = tid & 63;
  const int wave = tid >> 6;
  const int wm = (wave >> 1) * 64;   // wave row offset in tile
  const int wn = (wave & 1) * 32;    // wave col offset in tile
  const int fr = lane & 15;          // fragment row/col within 16
  const int fg = lane >> 4;          // k-group (0..3)

  f32x4 acc[4][2];
#pragma unroll
  for (int i = 0; i < 4; i++)
#pragma unroll
    for (int j = 0; j < 2; j++) acc[i][j] = (f32x4)(0.f);

  const int rs = tid >> 3;           // 0..31 staging row
  const int cs = (tid & 7) * 8;      // 0..56 staging col (16B chunks)

  for (int k0 = 0; k0 < K; k0 += BK) {
    __syncthreads();
#pragma unroll
    for (int i = 0; i < 4; i++) {
      int r = rs + i * 32;
      *(s16x8*)&As[r][cs] = *(const s16x8*)&A[(long)(m0 + r) * lda + k0 + cs];
    }
#pragma unroll
    for (int i = 0; i < 2; i++) {
      int r = rs + i * 32;
      *(s16x8*)&Bs[r][cs] = *(const s16x8*)&B[(long)(n0 + r) * ldb + k0 + cs];
    }
    __syncthreads();

#pragma unroll
    for (int ks = 0; ks < BK; ks += 32) {
      s16x8 av[4], bv[2];
#pragma unroll
      for (int mt = 0; mt < 4; mt++)
        av[mt] = *(const s16x8*)&As[wm + mt * 16 + fr][ks + fg * 8];
#pragma unroll
      for (int nt = 0; nt < 2; nt++)
        bv[nt] = *(const s16x8*)&Bs[wn + nt * 16 + fr][ks + fg * 8];
#pragma unroll
      for (int mt = 0; mt < 4; mt++)
#pragma unroll
        for (int nt = 0; nt < 2; nt++)
          acc[mt][nt] = __builtin_amdgcn_mfma_f32_16x16x32_bf16(
              av[mt], bv[nt], acc[mt][nt], 0, 0, 0);
    }
  }

  // Epilogue. D layout (verified m89): col = lane&15, row = (lane>>4)*4 + j
  if (OUT_F32) {
    float* C = (float*)Cptr + (long)bz * sCb;
#pragma unroll
    for (int mt = 0; mt < 4; mt++) {
      int row = m0 + wm + mt * 16 + fg * 4;
#pragma unroll
      for (int nt = 0; nt < 2; nt++) {
        int col = n0 + wn + nt * 16 + fr;
#pragma unroll
        for (int j = 0; j < 4; j++)
          C[(long)(row + j) * ldc + col] = acc[mt][nt][j];
      }
    }
  } else {
    unsigned short* C = (unsigned short*)Cptr + (long)bz * sCb;
#pragma unroll
    for (int mt = 0; mt < 4; mt++) {
      int row = m0 + wm + mt * 16 + fg * 4;
#pragma unroll
      for (int nt = 0; nt < 2; nt++) {
        int col = n0 + wn + nt * 16 + fr;
#pragma unroll
        for (int j = 0; j < 4; j++)
          C[(long)(row + j) * ldc + col] = f2bf(acc[mt][nt][j]);
      }
    }
  }
}

// ---------------------------------------------------------------------------
// Build XeT[b][f][k] (bf16) = f<512 ? x[b][k][f] : e[k][f-512]; optionally
// also Xe[b][k][f] (same values, untransposed) when workspace is roomy.
// 32x32 tiles via LDS.
// ---------------------------------------------------------------------------
__global__ __launch_bounds__(256) void convert_transpose(
    const float* __restrict__ x, const float* __restrict__ e,
    unsigned short* __restrict__ XeT, unsigned short* __restrict__ Xe)
{
  __shared__ unsigned short t[32][36];
  const int b  = blockIdx.z;
  const int k0 = blockIdx.x * 32;
  const int f0 = blockIdx.y * 32;
  const int r  = threadIdx.x >> 3;
  const int c4 = (threadIdx.x & 7) * 4;
  const int k = k0 + r, f = f0 + c4;

  float4 v;
  if (f < 512) v = *(const float4*)&x[((long)b * 2048 + k) * 512 + f];
  else         v = *(const float4*)&e[(long)k * 64 + (f - 512)];

  unsigned short h0 = f2bf(v.x), h1 = f2bf(v.y), h2 = f2bf(v.z), h3 = f2bf(v.w);
  if (Xe) {
    s16x4 o; o[0] = h0; o[1] = h1; o[2] = h2; o[3] = h3;
    *(s16x4*)&Xe[((long)b * 2048 + k) * 576 + f] = o;
  }
  t[r][c4 + 0] = h0; t[r][c4 + 1] = h1; t[r][c4 + 2] = h2; t[r][c4 + 3] = h3;
  __syncthreads();
  s16x4 o2;
#pragma unroll
  for (int j = 0; j < 4; j++) o2[j] = t[c4 + j][r];
  *(s16x4*)&XeT[((long)b * 576 + f0 + r) * 2048 + k0 + c4] = o2;
}

// Xe only (staged path: reuses XeT's space after stage 1 has consumed it)
__global__ __launch_bounds__(256) void convert_xe(
    const float* __restrict__ x, const float* __restrict__ e,
    unsigned short* __restrict__ Xe)
{
  long g = (long)blockIdx.x * 256 + threadIdx.x;  // 16*2048*144 total
  int  c4 = (int)(g % 144);
  long bn = g / 144;
  int  n  = (int)(bn % 2048);
  int  f  = c4 * 4;
  float4 v = (f < 512) ? *(const float4*)&x[bn * 512 + f]
                       : *(const float4*)&e[(long)n * 64 + (f - 512)];
  s16x4 o; o[0] = f2bf(v.x); o[1] = f2bf(v.y); o[2] = f2bf(v.z); o[3] = f2bf(v.w);
  *(s16x4*)&Xe[bn * 576 + f] = o;
}

// ---------------------------------------------------------------------------
// Wb[m][k] = Wbig[m][k] (576x576 bf16):
//  m<512,k<512 : relu(triu(W0,1))[k][m] = (m>k) ? relu(W0[k][m]) : 0
//  m<512,k>=512: W1[k-512][m]
//  m>=512,k<512: W2[k][m-512]
//  m>=512,k>=512: W3[k-512][m-512]
// ---------------------------------------------------------------------------
__global__ __launch_bounds__(256) void build_wb(
    const float* __restrict__ W0, const float* __restrict__ W1,
    const float* __restrict__ W2, const float* __restrict__ W3,
    unsigned short* __restrict__ Wb)
{
  int idx = blockIdx.x * 256 + threadIdx.x;  // < 331776
  int m = idx / 576, k = idx % 576;
  float v;
  if (m < 512)
    v = (k < 512) ? ((m > k) ? fmaxf(W0[k * 512 + m], 0.f) : 0.f)
                  : W1[(k - 512) * 512 + m];
  else
    v = (k < 512) ? W2[k * 64 + (m - 512)]
                  : W3[(k - 512) * 64 + (m - 512)];
  Wb[idx] = f2bf(v);
}

// ---------------------------------------------------------------------------
extern "C" void kernel_launch(void* const* d_in, const int* in_sizes, int n_in,
                              void* d_out, int out_size, void* d_ws, size_t ws_size,
                              hipStream_t stream) {
  const float* x  = (const float*)d_in[0];
  const float* e  = (const float*)d_in[1];
  const float* W0 = (const float*)d_in[2];
  const float* W1 = (const float*)d_in[3];
  const float* W2 = (const float*)d_in[4];
  const float* W3 = (const float*)d_in[5];
  float* out = (float*)d_out;

  const size_t SZ_XeT = (size_t)16 * 576 * 2048 * 2;  // 37,748,736
  const size_t SZ_CT  = (size_t)16 * 512 * 576 * 2;   //  9,437,184
  const size_t SZ_DT  = SZ_CT;
  const size_t SZ_WB  = (size_t)576 * 576 * 2;        //    663,552

  char* p = (char*)d_ws;
  unsigned short* XeT = (unsigned short*)p;  p += SZ_XeT;
  unsigned short* CT  = (unsigned short*)p;  p += SZ_CT;
  unsigned short* DT  = (unsigned short*)p;  p += SZ_DT;
  unsigned short* Wb  = (unsigned short*)p;  p += SZ_WB;
  const size_t base = SZ_XeT + SZ_CT + SZ_DT + SZ_WB; // 57,286,656
  if (ws_size < base) return;  // insufficient workspace -> loud failure
  const bool roomy = ws_size >= base + SZ_XeT;
  unsigned short* Xe = roomy ? (unsigned short*)p : XeT;

  build_wb<<<1296, 256, 0, stream>>>(W0, W1, W2, W3, Wb);
  convert_transpose<<<dim3(64, 18, 16), 256, 0, stream>>>(x, e, XeT,
                                                          roomy ? Xe : nullptr);

  // Stage 1: CT[n][f] = sum_k XeT[n][k]*XeT[f][k]   (M=512, N=576, K=2048)
  gemm_nt<0><<<dim3(4, 9, 16), 256, 0, stream>>>(
      XeT, (long)576 * 2048, 2048,
      XeT, (long)576 * 2048, 2048,
      CT,  (long)512 * 576, 576, 2048);

  if (!roomy)
    convert_xe<<<18432, 256, 0, stream>>>(x, e, Xe);

  // Stage 2: DT[t][m] = sum_f CT[t][f]*Wb[m][f]     (M=512, N=576, K=576)
  gemm_nt<0><<<dim3(4, 9, 16), 256, 0, stream>>>(
      CT, (long)512 * 576, 576,
      Wb, 0L, 576,
      DT, (long)512 * 576, 576, 576);

  // Stage 3: out[n][t] = sum_m Xe[n][m]*DT[t][m]    (M=2048, N=512, K=576)
  gemm_nt<1><<<dim3(16, 8, 16), 256, 0, stream>>>(
      Xe, (long)2048 * 576, 576,
      DT, (long)512 * 576, 576,
      out, (long)2048 * 512, 512, 576);
}

// Round 2
// 124.815 us; speedup vs baseline: 1.0204x; 1.0204x over previous
//
#include <hip/hip_runtime.h>
#include <hip/hip_bf16.h>

// B=16, N=2048, DIM_X=512, DIM_E=64, F=576 (=512+64)
// out_b = Xe_b * (Wbig * (Xe_b^T x_b))  -- three NT-GEMMs, no NxN matrix.

typedef __attribute__((ext_vector_type(8))) short s16x8;
typedef __attribute__((ext_vector_type(4))) short s16x4;
typedef __attribute__((ext_vector_type(4))) float f32x4;

__device__ __forceinline__ unsigned short f2bf(float f) {
  union { float f; unsigned u; } v; v.f = f;
  unsigned r = v.u + 0x7fff + ((v.u >> 16) & 1);   // RNE
  return (unsigned short)(r >> 16);
}

// ---------------------------------------------------------------------------
// NT-GEMM, m97 structure: C[i][j] = sum_k A[i][k]*B[j][k].
// A: M x K row-major, B: N x K row-major, both bf16; C: M x N (bf16 or f32).
// TM x TN tile, BK=64, 256 threads = 4 waves (2x2), wave tile TM/2 x TN/2.
// Staging via global_load_lds dwordx4 into linear LDS (no padding).
// M%TM==0, N%TN==0, K%64==0.
// ---------------------------------------------------------------------------
template<int TM, int TN, int OUT_F32>
__global__ __launch_bounds__(256) void gemm_nt(
    const unsigned short* __restrict__ A, long sAb, int lda,
    const unsigned short* __restrict__ B, long sBb, int ldb,
    void* __restrict__ Cptr, long sCb, int ldc,
    int K)
{
  constexpr int TK = 64;
  constexpr int WM = TM / 2, WN = TN / 2;     // wave tile
  constexpr int AM = WM / 16, AN = WN / 16;   // fragments per wave
  constexpr int ACH = TM / 8;                 // 1024B staging chunks (8 rows each)
  constexpr int BCH = TN / 8;

  __shared__ unsigned short As[TM * TK];
  __shared__ unsigned short Bs[TN * TK];

  const int bz = blockIdx.z;
  const unsigned short* Ab = A + (long)bz * sAb;
  const unsigned short* Bb = B + (long)bz * sBb;
  const int m0 = blockIdx.x * TM;
  const int n0 = blockIdx.y * TN;

  const int tid  = threadIdx.x;
  const int lane = tid & 63;
  const int wave = tid >> 6;
  const int wm = (wave >> 1) * WM;
  const int wn = (wave & 1) * WN;
  const int fr = lane & 15;          // fragment row/col within 16
  const int fg = lane >> 4;          // k-group (0..3)

  const int srow = lane >> 3;        // 0..7  (row within 8-row chunk)
  const int scol = (lane & 7) * 8;   // 0..56 (bf16 col, 16B granules)

  f32x4 acc[AM][AN];
#pragma unroll
  for (int i = 0; i < AM; i++)
#pragma unroll
    for (int j = 0; j < AN; j++) acc[i][j] = (f32x4)(0.f);

  for (int k0 = 0; k0 < K; k0 += TK) {
    __syncthreads();
#pragma unroll
    for (int i = 0; i < ACH / 4; i++) {
      const int c = wave * (ACH / 4) + i;
      __builtin_amdgcn_global_load_lds(
          (const __attribute__((address_space(1))) unsigned*)
              (Ab + (long)(m0 + c * 8 + srow) * lda + k0 + scol),
          (__attribute__((address_space(3))) unsigned*)(&As[c * 512]),
          16, 0, 0);
    }
#pragma unroll
    for (int i = 0; i < BCH / 4; i++) {
      const int c = wave * (BCH / 4) + i;
      __builtin_amdgcn_global_load_lds(
          (const __attribute__((address_space(1))) unsigned*)
              (Bb + (long)(n0 + c * 8 + srow) * ldb + k0 + scol),
          (__attribute__((address_space(3))) unsigned*)(&Bs[c * 512]),
          16, 0, 0);
    }
    __syncthreads();   // compiler emits vmcnt(0) drain before barrier

#pragma unroll
    for (int ks = 0; ks < TK; ks += 32) {
      s16x8 av[AM], bv[AN];
#pragma unroll
      for (int mt = 0; mt < AM; mt++)
        av[mt] = *(const s16x8*)&As[(wm + mt * 16 + fr) * TK + ks + fg * 8];
#pragma unroll
      for (int nt = 0; nt < AN; nt++)
        bv[nt] = *(const s16x8*)&Bs[(wn + nt * 16 + fr) * TK + ks + fg * 8];
#pragma unroll
      for (int mt = 0; mt < AM; mt++)
#pragma unroll
        for (int nt = 0; nt < AN; nt++)
          acc[mt][nt] = __builtin_amdgcn_mfma_f32_16x16x32_bf16(
              av[mt], bv[nt], acc[mt][nt], 0, 0, 0);
    }
  }

  // D layout (verified m89): col = lane&15, row = (lane>>4)*4 + j
  if (OUT_F32) {
    float* C = (float*)Cptr + (long)bz * sCb;
#pragma unroll
    for (int mt = 0; mt < AM; mt++) {
      const int row = m0 + wm + mt * 16 + fg * 4;
#pragma unroll
      for (int nt = 0; nt < AN; nt++) {
        const int col = n0 + wn + nt * 16 + fr;
#pragma unroll
        for (int j = 0; j < 4; j++)
          C[(long)(row + j) * ldc + col] = acc[mt][nt][j];
      }
    }
  } else {
    unsigned short* C = (unsigned short*)Cptr + (long)bz * sCb;
#pragma unroll
    for (int mt = 0; mt < AM; mt++) {
      const int row = m0 + wm + mt * 16 + fg * 4;
#pragma unroll
      for (int nt = 0; nt < AN; nt++) {
        const int col = n0 + wn + nt * 16 + fr;
#pragma unroll
        for (int j = 0; j < 4; j++)
          C[(long)(row + j) * ldc + col] = f2bf(acc[mt][nt][j]);
      }
    }
  }
}

// ---------------------------------------------------------------------------
// XeT[b][f][k] = f<512 ? x[b][k][f] : e[k][f-512]  (bf16), and optionally
// Xe[b][k][f] (untransposed) when workspace is roomy. 32x32 tiles via LDS.
// ---------------------------------------------------------------------------
__global__ __launch_bounds__(256) void convert_transpose(
    const float* __restrict__ x, const float* __restrict__ e,
    unsigned short* __restrict__ XeT, unsigned short* __restrict__ Xe)
{
  __shared__ unsigned short t[32][36];
  const int b  = blockIdx.z;
  const int k0 = blockIdx.x * 32;
  const int f0 = blockIdx.y * 32;
  const int r  = threadIdx.x >> 3;
  const int c4 = (threadIdx.x & 7) * 4;
  const int k = k0 + r, f = f0 + c4;

  float4 v;
  if (f < 512) v = *(const float4*)&x[((long)b * 2048 + k) * 512 + f];
  else         v = *(const float4*)&e[(long)k * 64 + (f - 512)];

  unsigned short h0 = f2bf(v.x), h1 = f2bf(v.y), h2 = f2bf(v.z), h3 = f2bf(v.w);
  if (Xe) {
    s16x4 o; o[0] = h0; o[1] = h1; o[2] = h2; o[3] = h3;
    *(s16x4*)&Xe[((long)b * 2048 + k) * 576 + f] = o;
  }
  t[r][c4 + 0] = h0; t[r][c4 + 1] = h1; t[r][c4 + 2] = h2; t[r][c4 + 3] = h3;
  __syncthreads();
  s16x4 o2;
#pragma unroll
  for (int j = 0; j < 4; j++) o2[j] = t[c4 + j][r];
  *(s16x4*)&XeT[((long)b * 576 + f0 + r) * 2048 + k0 + c4] = o2;
}

__global__ __launch_bounds__(256) void convert_xe(
    const float* __restrict__ x, const float* __restrict__ e,
    unsigned short* __restrict__ Xe)
{
  long g = (long)blockIdx.x * 256 + threadIdx.x;  // 16*2048*144 total
  int  c4 = (int)(g % 144);
  long bn = g / 144;
  int  n  = (int)(bn % 2048);
  int  f  = c4 * 4;
  float4 v = (f < 512) ? *(const float4*)&x[bn * 512 + f]
                       : *(const float4*)&e[(long)n * 64 + (f - 512)];
  s16x4 o; o[0] = f2bf(v.x); o[1] = f2bf(v.y); o[2] = f2bf(v.z); o[3] = f2bf(v.w);
  *(s16x4*)&Xe[bn * 576 + f] = o;
}

// ---------------------------------------------------------------------------
// Wb[m][k] (576x576 bf16):
//  m<512,k<512 : (m>k) ? relu(W0[k][m]) : 0        (relu(triu(W0,1)) transposed)
//  m<512,k>=512: W1[k-512][m]
//  m>=512,k<512: W2[k][m-512]
//  m>=512,k>=512: W3[k-512][m-512]
// ---------------------------------------------------------------------------
__global__ __launch_bounds__(256) void build_wb(
    const float* __restrict__ W0, const float* __restrict__ W1,
    const float* __restrict__ W2, const float* __restrict__ W3,
    unsigned short* __restrict__ Wb)
{
  int idx = blockIdx.x * 256 + threadIdx.x;  // < 331776
  int m = idx / 576, k = idx % 576;
  float v;
  if (m < 512)
    v = (k < 512) ? ((m > k) ? fmaxf(W0[k * 512 + m], 0.f) : 0.f)
                  : W1[(k - 512) * 512 + m];
  else
    v = (k < 512) ? W2[k * 64 + (m - 512)]
                  : W3[(k - 512) * 64 + (m - 512)];
  Wb[idx] = f2bf(v);
}

// ---------------------------------------------------------------------------
extern "C" void kernel_launch(void* const* d_in, const int* in_sizes, int n_in,
                              void* d_out, int out_size, void* d_ws, size_t ws_size,
                              hipStream_t stream) {
  const float* x  = (const float*)d_in[0];
  const float* e  = (const float*)d_in[1];
  const float* W0 = (const float*)d_in[2];
  const float* W1 = (const float*)d_in[3];
  const float* W2 = (const float*)d_in[4];
  const float* W3 = (const float*)d_in[5];
  float* out = (float*)d_out;

  const size_t SZ_XeT = (size_t)16 * 576 * 2048 * 2;  // 37,748,736
  const size_t SZ_CT  = (size_t)16 * 512 * 576 * 2;   //  9,437,184
  const size_t SZ_DT  = SZ_CT;
  const size_t SZ_WB  = (size_t)576 * 576 * 2;        //    663,552

  char* p = (char*)d_ws;
  unsigned short* XeT = (unsigned short*)p;  p += SZ_XeT;
  unsigned short* CT  = (unsigned short*)p;  p += SZ_CT;
  unsigned short* DT  = (unsigned short*)p;  p += SZ_DT;
  unsigned short* Wb  = (unsigned short*)p;  p += SZ_WB;
  const size_t base = SZ_XeT + SZ_CT + SZ_DT + SZ_WB;
  if (ws_size < base) return;  // insufficient workspace -> loud failure
  const bool roomy = ws_size >= base + SZ_XeT;
  unsigned short* Xe = roomy ? (unsigned short*)p : XeT;

  build_wb<<<1296, 256, 0, stream>>>(W0, W1, W2, W3, Wb);
  convert_transpose<<<dim3(64, 18, 16), 256, 0, stream>>>(x, e, XeT,
                                                          roomy ? Xe : nullptr);

  // Stage 1: CT[i][j] = sum_k XeT[i][k]*XeT[j][k]   (M=512, N=576, K=2048)
  gemm_nt<64, 96, 0><<<dim3(8, 6, 16), 256, 0, stream>>>(
      XeT, (long)576 * 2048, 2048,
      XeT, (long)576 * 2048, 2048,
      CT,  (long)512 * 576, 576, 2048);

  if (!roomy)
    convert_xe<<<18432, 256, 0, stream>>>(x, e, Xe);

  // Stage 2: DT[t][m] = sum_f CT[t][f]*Wb[m][f]     (M=512, N=576, K=576)
  gemm_nt<64, 96, 0><<<dim3(8, 6, 16), 256, 0, stream>>>(
      CT, (long)512 * 576, 576,
      Wb, 0L, 576,
      DT, (long)512 * 576, 576, 576);

  // Stage 3: out[n][t] = sum_m Xe[n][m]*DT[t][m]    (M=2048, N=512, K=576)
  gemm_nt<128, 128, 1><<<dim3(16, 4, 16), 256, 0, stream>>>(
      Xe, (long)2048 * 576, 576,
      DT, (long)512 * 576, 576,
      out, (long)2048 * 512, 512, 576);
}

// Round 3
// 95.765 us; speedup vs baseline: 1.3300x; 1.3034x over previous
//
#include <hip/hip_runtime.h>
#include <hip/hip_bf16.h>

// B=16, N=2048, DIM_X=512, DIM_E=64, F=576 (=512+64)
// out_b = Xe_b * (Wbig * (Xe_b^T x_b))  -- three NT-GEMMs, no NxN matrix.

typedef __attribute__((ext_vector_type(8))) short s16x8;
typedef __attribute__((ext_vector_type(4))) short s16x4;
typedef __attribute__((ext_vector_type(4))) float f32x4;

__device__ __forceinline__ unsigned short f2bf(float f) {
  union { float f; unsigned u; } v; v.f = f;
  unsigned r = v.u + 0x7fff + ((v.u >> 16) & 1);   // RNE
  return (unsigned short)(r >> 16);
}

// ---------------------------------------------------------------------------
// NT-GEMM: C[i][j] = sum_k A[i][k]*B[j][k]. A: MxK, B: NxK row-major bf16;
// C: MxN (bf16 or f32). TMxTN tile, TK=64, 256 threads = 4 waves (2x2).
// - global_load_lds width-16 staging, double-buffered LDS, prefetch-before-
//   compute, ONE __syncthreads per K-tile (its vmcnt(0) drain is the wait).
// - LDS swizzle (both-sides, rule 21): 16B slot ^= (row&7). Linear LDS dest;
//   the global SOURCE column is pre-swizzled per lane; ds_read applies the
//   same XOR. Kills the 16-way fr-lane bank conflict of 128B rows.
// - XCD batch grouping: xcd = bid%8 handles batches {xcd, xcd+8}; per-batch
//   panels (~2.25MB) then fit one XCD's 4MB L2.
// ---------------------------------------------------------------------------
template<int TM, int TN, int GX, int GY, int OUT_F32>
__global__ __launch_bounds__(256) void gemm_nt(
    const unsigned short* __restrict__ A, long sAb, int lda,
    const unsigned short* __restrict__ B, long sBb, int ldb,
    void* __restrict__ Cptr, long sCb, int ldc,
    int K)
{
  constexpr int TK = 64;
  constexpr int WM = TM / 2, WN = TN / 2;     // wave tile
  constexpr int AM = WM / 16, AN = WN / 16;   // fragments per wave
  constexpr int ACH = TM / 8;                 // 1024B staging chunks (8 rows)
  constexpr int BCH = TN / 8;
  constexpr int NBLK = GX * GY;

  __shared__ unsigned short As[2][TM * TK];
  __shared__ unsigned short Bs[2][TN * TK];

  // --- XCD-grouped block remap (grid = 16*NBLK, 1D) ---
  const int bid  = blockIdx.x;
  const int xcd  = bid & 7;
  const int slot = bid >> 3;                  // 0 .. 2*NBLK-1
  const int bz   = xcd + 8 * (slot / NBLK);   // batch
  const int tix  = slot % NBLK;
  const int m0   = (tix % GX) * TM;
  const int n0   = (tix / GX) * TN;

  const unsigned short* Ab = A + (long)bz * sAb;
  const unsigned short* Bb = B + (long)bz * sBb;

  const int tid  = threadIdx.x;
  const int lane = tid & 63;
  const int wave = tid >> 6;
  const int wm = (wave >> 1) * WM;
  const int wn = (wave & 1) * WN;
  const int fr = lane & 15;          // fragment row within 16
  const int fg = lane >> 4;          // k-group (0..3)
  const int fx = fr & 7;             // row bits for swizzle

  // staging: chunk = 8 rows x 128B; lane l -> dest byte c*1024 + l*16.
  // dest slot (l&7) must hold logical slot (l&7)^(row&7), row&7 = l>>3 &7.
  const int srow = lane >> 3;                      // row within chunk
  const int scol = (((lane & 7) ^ (lane >> 3)) & 7) * 8;  // swizzled src col

  f32x4 acc[AM][AN];
#pragma unroll
  for (int i = 0; i < AM; i++)
#pragma unroll
    for (int j = 0; j < AN; j++) acc[i][j] = (f32x4)(0.f);

  auto stage = [&](int buf, int k0) {
#pragma unroll
    for (int i = 0; i < ACH / 4; i++) {
      const int c = wave * (ACH / 4) + i;
      __builtin_amdgcn_global_load_lds(
          (const __attribute__((address_space(1))) unsigned*)
              (Ab + (long)(m0 + c * 8 + srow) * lda + k0 + scol),
          (__attribute__((address_space(3))) unsigned*)(&As[buf][c * 512]),
          16, 0, 0);
    }
#pragma unroll
    for (int i = 0; i < BCH / 4; i++) {
      const int c = wave * (BCH / 4) + i;
      __builtin_amdgcn_global_load_lds(
          (const __attribute__((address_space(1))) unsigned*)
              (Bb + (long)(n0 + c * 8 + srow) * ldb + k0 + scol),
          (__attribute__((address_space(3))) unsigned*)(&Bs[buf][c * 512]),
          16, 0, 0);
    }
  };

  const int NT = K / TK;
  stage(0, 0);
  __syncthreads();                       // drain prologue loads

  for (int t = 0; t < NT; ++t) {
    const int cur = t & 1;
    if (t + 1 < NT) stage(cur ^ 1, (t + 1) * TK);   // prefetch next tile

    const unsigned short* Ac = &As[cur][0];
    const unsigned short* Bc = &Bs[cur][0];
#pragma unroll
    for (int ks = 0; ks < 2; ks++) {     // k-halves of the 64-tile
      s16x8 av[AM], bv[AN];
#pragma unroll
      for (int mt = 0; mt < AM; mt++)
        av[mt] = *(const s16x8*)
            &Ac[(wm + mt * 16 + fr) * TK + (((ks * 4 + fg) ^ fx) * 8)];
#pragma unroll
      for (int nt = 0; nt < AN; nt++)
        bv[nt] = *(const s16x8*)
            &Bc[(wn + nt * 16 + fr) * TK + (((ks * 4 + fg) ^ fx) * 8)];
#pragma unroll
      for (int mt = 0; mt < AM; mt++)
#pragma unroll
        for (int nt = 0; nt < AN; nt++)
          acc[mt][nt] = __builtin_amdgcn_mfma_f32_16x16x32_bf16(
              av[mt], bv[nt], acc[mt][nt], 0, 0, 0);
    }
    __syncthreads();   // vmcnt(0)+lgkmcnt(0) drain: prefetch landed, reads done
  }

  // D layout (verified m89): col = lane&15, row = (lane>>4)*4 + j
  if (OUT_F32) {
    float* C = (float*)Cptr + (long)bz * sCb;
#pragma unroll
    for (int mt = 0; mt < AM; mt++) {
      const int row = m0 + wm + mt * 16 + fg * 4;
#pragma unroll
      for (int nt = 0; nt < AN; nt++) {
        const int col = n0 + wn + nt * 16 + fr;
#pragma unroll
        for (int j = 0; j < 4; j++)
          C[(long)(row + j) * ldc + col] = acc[mt][nt][j];
      }
    }
  } else {
    unsigned short* C = (unsigned short*)Cptr + (long)bz * sCb;
#pragma unroll
    for (int mt = 0; mt < AM; mt++) {
      const int row = m0 + wm + mt * 16 + fg * 4;
#pragma unroll
      for (int nt = 0; nt < AN; nt++) {
        const int col = n0 + wn + nt * 16 + fr;
#pragma unroll
        for (int j = 0; j < 4; j++)
          C[(long)(row + j) * ldc + col] = f2bf(acc[mt][nt][j]);
      }
    }
  }
}

// ---------------------------------------------------------------------------
// XeT[b][f][k] = f<512 ? x[b][k][f] : e[k][f-512]  (bf16), and optionally
// Xe[b][k][f] (untransposed) when workspace is roomy. 32x32 tiles via LDS.
// ---------------------------------------------------------------------------
__global__ __launch_bounds__(256) void convert_transpose(
    const float* __restrict__ x, const float* __restrict__ e,
    unsigned short* __restrict__ XeT, unsigned short* __restrict__ Xe)
{
  __shared__ unsigned short t[32][36];
  const int b  = blockIdx.z;
  const int k0 = blockIdx.x * 32;
  const int f0 = blockIdx.y * 32;
  const int r  = threadIdx.x >> 3;
  const int c4 = (threadIdx.x & 7) * 4;
  const int k = k0 + r, f = f0 + c4;

  float4 v;
  if (f < 512) v = *(const float4*)&x[((long)b * 2048 + k) * 512 + f];
  else         v = *(const float4*)&e[(long)k * 64 + (f - 512)];

  unsigned short h0 = f2bf(v.x), h1 = f2bf(v.y), h2 = f2bf(v.z), h3 = f2bf(v.w);
  if (Xe) {
    s16x4 o; o[0] = h0; o[1] = h1; o[2] = h2; o[3] = h3;
    *(s16x4*)&Xe[((long)b * 2048 + k) * 576 + f] = o;
  }
  t[r][c4 + 0] = h0; t[r][c4 + 1] = h1; t[r][c4 + 2] = h2; t[r][c4 + 3] = h3;
  __syncthreads();
  s16x4 o2;
#pragma unroll
  for (int j = 0; j < 4; j++) o2[j] = t[c4 + j][r];
  *(s16x4*)&XeT[((long)b * 576 + f0 + r) * 2048 + k0 + c4] = o2;
}

__global__ __launch_bounds__(256) void convert_xe(
    const float* __restrict__ x, const float* __restrict__ e,
    unsigned short* __restrict__ Xe)
{
  long g = (long)blockIdx.x * 256 + threadIdx.x;  // 16*2048*144 total
  int  c4 = (int)(g % 144);
  long bn = g / 144;
  int  n  = (int)(bn % 2048);
  int  f  = c4 * 4;
  float4 v = (f < 512) ? *(const float4*)&x[bn * 512 + f]
                       : *(const float4*)&e[(long)n * 64 + (f - 512)];
  s16x4 o; o[0] = f2bf(v.x); o[1] = f2bf(v.y); o[2] = f2bf(v.z); o[3] = f2bf(v.w);
  *(s16x4*)&Xe[bn * 576 + f] = o;
}

// ---------------------------------------------------------------------------
// Wb[m][k] (576x576 bf16):
//  m<512,k<512 : (m>k) ? relu(W0[k][m]) : 0        (relu(triu(W0,1)) transposed)
//  m<512,k>=512: W1[k-512][m]
//  m>=512,k<512: W2[k][m-512]
//  m>=512,k>=512: W3[k-512][m-512]
// ---------------------------------------------------------------------------
__global__ __launch_bounds__(256) void build_wb(
    const float* __restrict__ W0, const float* __restrict__ W1,
    const float* __restrict__ W2, const float* __restrict__ W3,
    unsigned short* __restrict__ Wb)
{
  int idx = blockIdx.x * 256 + threadIdx.x;  // < 331776
  int m = idx / 576, k = idx % 576;
  float v;
  if (m < 512)
    v = (k < 512) ? ((m > k) ? fmaxf(W0[k * 512 + m], 0.f) : 0.f)
                  : W1[(k - 512) * 512 + m];
  else
    v = (k < 512) ? W2[k * 64 + (m - 512)]
                  : W3[(k - 512) * 64 + (m - 512)];
  Wb[idx] = f2bf(v);
}

// ---------------------------------------------------------------------------
extern "C" void kernel_launch(void* const* d_in, const int* in_sizes, int n_in,
                              void* d_out, int out_size, void* d_ws, size_t ws_size,
                              hipStream_t stream) {
  const float* x  = (const float*)d_in[0];
  const float* e  = (const float*)d_in[1];
  const float* W0 = (const float*)d_in[2];
  const float* W1 = (const float*)d_in[3];
  const float* W2 = (const float*)d_in[4];
  const float* W3 = (const float*)d_in[5];
  float* out = (float*)d_out;

  const size_t SZ_XeT = (size_t)16 * 576 * 2048 * 2;  // 37,748,736
  const size_t SZ_CT  = (size_t)16 * 512 * 576 * 2;   //  9,437,184
  const size_t SZ_DT  = SZ_CT;
  const size_t SZ_WB  = (size_t)576 * 576 * 2;        //    663,552

  char* p = (char*)d_ws;
  unsigned short* XeT = (unsigned short*)p;  p += SZ_XeT;
  unsigned short* CT  = (unsigned short*)p;  p += SZ_CT;
  unsigned short* DT  = (unsigned short*)p;  p += SZ_DT;
  unsigned short* Wb  = (unsigned short*)p;  p += SZ_WB;
  const size_t base = SZ_XeT + SZ_CT + SZ_DT + SZ_WB;
  if (ws_size < base) return;  // insufficient workspace -> loud failure
  const bool roomy = ws_size >= base + SZ_XeT;
  unsigned short* Xe = roomy ? (unsigned short*)p : XeT;

  build_wb<<<1296, 256, 0, stream>>>(W0, W1, W2, W3, Wb);
  convert_transpose<<<dim3(64, 18, 16), 256, 0, stream>>>(x, e, XeT,
                                                          roomy ? Xe : nullptr);

  // Stage 1: CT[i][j] = sum_k XeT[i][k]*XeT[j][k]   (M=512, N=576, K=2048)
  gemm_nt<64, 96, 8, 6, 0><<<768, 256, 0, stream>>>(
      XeT, (long)576 * 2048, 2048,
      XeT, (long)576 * 2048, 2048,
      CT,  (long)512 * 576, 576, 2048);

  if (!roomy)
    convert_xe<<<18432, 256, 0, stream>>>(x, e, Xe);

  // Stage 2: DT[t][m] = sum_f CT[t][f]*Wb[m][f]     (M=512, N=576, K=576)
  gemm_nt<64, 96, 8, 6, 0><<<768, 256, 0, stream>>>(
      CT, (long)512 * 576, 576,
      Wb, 0L, 576,
      DT, (long)512 * 576, 576, 576);

  // Stage 3: out[n][t] = sum_m Xe[n][m]*DT[t][m]    (M=2048, N=512, K=576)
  gemm_nt<128, 128, 16, 4, 1><<<1024, 256, 0, stream>>>(
      Xe, (long)2048 * 576, 576,
      DT, (long)512 * 576, 576,
      out, (long)2048 * 512, 512, 576);
}

// Round 4
// 93.986 us; speedup vs baseline: 1.3551x; 1.0189x over previous
//
#include <hip/hip_runtime.h>
#include <hip/hip_bf16.h>

// B=16, N=2048, DIM_X=512, DIM_E=64, F=576 (=512+64)
// out_b = Xe_b * (Wbig * (Xe_b^T x_b))  -- three NT-GEMMs, no NxN matrix.

typedef __attribute__((ext_vector_type(8))) short s16x8;
typedef __attribute__((ext_vector_type(4))) short s16x4;
typedef __attribute__((ext_vector_type(4))) float f32x4;

__device__ __forceinline__ unsigned short f2bf(float f) {
  union { float f; unsigned u; } v; v.f = f;
  unsigned r = v.u + 0x7fff + ((v.u >> 16) & 1);   // RNE
  return (unsigned short)(r >> 16);
}

// ---------------------------------------------------------------------------
// NT-GEMM: C[i][j] = sum_k A[i][k]*B[j][k]. A: MxK, B: NxK row-major bf16;
// C: MxN (bf16 or f32). TMxTN tile, TK=64, 256 threads = 4 waves (2x2).
// global_load_lds w16 staging, dbuf LDS, prefetch-before-compute, one
// __syncthreads per K-tile. LDS swizzle both-sides (16B slot ^= row&7) via
// pre-swizzled global source. XCD batch grouping (bid&7 -> batches {x,x+8}).
// ---------------------------------------------------------------------------
template<int TM, int TN, int GX, int GY, int OUT_F32>
__global__ __launch_bounds__(256) void gemm_nt(
    const unsigned short* __restrict__ A, long sAb, int lda,
    const unsigned short* __restrict__ B, long sBb, int ldb,
    void* __restrict__ Cptr, long sCb, int ldc,
    int K)
{
  constexpr int TK = 64;
  constexpr int WM = TM / 2, WN = TN / 2;
  constexpr int AM = WM / 16, AN = WN / 16;
  constexpr int ACH = TM / 8;
  constexpr int BCH = TN / 8;
  constexpr int NBLK = GX * GY;

  __shared__ unsigned short As[2][TM * TK];
  __shared__ unsigned short Bs[2][TN * TK];

  const int bid  = blockIdx.x;
  const int xcd  = bid & 7;
  const int slot = bid >> 3;
  const int bz   = xcd + 8 * (slot / NBLK);
  const int tix  = slot % NBLK;
  const int m0   = (tix % GX) * TM;
  const int n0   = (tix / GX) * TN;

  const unsigned short* Ab = A + (long)bz * sAb;
  const unsigned short* Bb = B + (long)bz * sBb;

  const int tid  = threadIdx.x;
  const int lane = tid & 63;
  const int wave = tid >> 6;
  const int wm = (wave >> 1) * WM;
  const int wn = (wave & 1) * WN;
  const int fr = lane & 15;
  const int fg = lane >> 4;
  const int fx = fr & 7;

  const int srow = lane >> 3;
  const int scol = (((lane & 7) ^ (lane >> 3)) & 7) * 8;

  f32x4 acc[AM][AN];
#pragma unroll
  for (int i = 0; i < AM; i++)
#pragma unroll
    for (int j = 0; j < AN; j++) acc[i][j] = (f32x4)(0.f);

  auto stage = [&](int buf, int k0) {
#pragma unroll
    for (int i = 0; i < ACH / 4; i++) {
      const int c = wave * (ACH / 4) + i;
      __builtin_amdgcn_global_load_lds(
          (const __attribute__((address_space(1))) unsigned*)
              (Ab + (long)(m0 + c * 8 + srow) * lda + k0 + scol),
          (__attribute__((address_space(3))) unsigned*)(&As[buf][c * 512]),
          16, 0, 0);
    }
#pragma unroll
    for (int i = 0; i < BCH / 4; i++) {
      const int c = wave * (BCH / 4) + i;
      __builtin_amdgcn_global_load_lds(
          (const __attribute__((address_space(1))) unsigned*)
              (Bb + (long)(n0 + c * 8 + srow) * ldb + k0 + scol),
          (__attribute__((address_space(3))) unsigned*)(&Bs[buf][c * 512]),
          16, 0, 0);
    }
  };

  const int NT = K / TK;
  stage(0, 0);
  __syncthreads();

  for (int t = 0; t < NT; ++t) {
    const int cur = t & 1;
    if (t + 1 < NT) stage(cur ^ 1, (t + 1) * TK);

    const unsigned short* Ac = &As[cur][0];
    const unsigned short* Bc = &Bs[cur][0];
#pragma unroll
    for (int ks = 0; ks < 2; ks++) {
      s16x8 av[AM], bv[AN];
#pragma unroll
      for (int mt = 0; mt < AM; mt++)
        av[mt] = *(const s16x8*)
            &Ac[(wm + mt * 16 + fr) * TK + (((ks * 4 + fg) ^ fx) * 8)];
#pragma unroll
      for (int nt = 0; nt < AN; nt++)
        bv[nt] = *(const s16x8*)
            &Bc[(wn + nt * 16 + fr) * TK + (((ks * 4 + fg) ^ fx) * 8)];
#pragma unroll
      for (int mt = 0; mt < AM; mt++)
#pragma unroll
        for (int nt = 0; nt < AN; nt++)
          acc[mt][nt] = __builtin_amdgcn_mfma_f32_16x16x32_bf16(
              av[mt], bv[nt], acc[mt][nt], 0, 0, 0);
    }
    __syncthreads();
  }

  // D layout (verified m89): col = lane&15, row = (lane>>4)*4 + j
  if (OUT_F32) {
    float* C = (float*)Cptr + (long)bz * sCb;
#pragma unroll
    for (int mt = 0; mt < AM; mt++) {
      const int row = m0 + wm + mt * 16 + fg * 4;
#pragma unroll
      for (int nt = 0; nt < AN; nt++) {
        const int col = n0 + wn + nt * 16 + fr;
#pragma unroll
        for (int j = 0; j < 4; j++)
          C[(long)(row + j) * ldc + col] = acc[mt][nt][j];
      }
    }
  } else {
    unsigned short* C = (unsigned short*)Cptr + (long)bz * sCb;
#pragma unroll
    for (int mt = 0; mt < AM; mt++) {
      const int row = m0 + wm + mt * 16 + fg * 4;
#pragma unroll
      for (int nt = 0; nt < AN; nt++) {
        const int col = n0 + wn + nt * 16 + fr;
#pragma unroll
        for (int j = 0; j < 4; j++)
          C[(long)(row + j) * ldc + col] = f2bf(acc[mt][nt][j]);
      }
    }
  }
}

// ---------------------------------------------------------------------------
// Fused convert: per 64x64 tile, read x/e (f32), write Xe (bf16) directly
// from registers (coalesced 128B runs), and XeT (bf16 transposed) via an LDS
// tile. Pad=2 elems -> 132B row stride (scalar-gather conflicts ~4-way max).
// ---------------------------------------------------------------------------
__global__ __launch_bounds__(256) void convert_fused(
    const float* __restrict__ x, const float* __restrict__ e,
    unsigned short* __restrict__ XeT, unsigned short* __restrict__ Xe)
{
  constexpr int LP = 66;             // row stride in elems (64 + 2 pad)
  __shared__ unsigned short t[64 * LP];
  const int b  = blockIdx.z;
  const int k0 = blockIdx.x * 64;
  const int f0 = blockIdx.y * 64;
  const int l  = threadIdx.x & 63;
  const int w  = threadIdx.x >> 6;
  const int fi = (l & 15) * 4;
  const int f  = f0 + fi;

#pragma unroll
  for (int it = 0; it < 4; ++it) {
    const int row = w * 16 + it * 4 + (l >> 4);
    const int k = k0 + row;
    float4 v = (f < 512) ? *(const float4*)&x[((long)b * 2048 + k) * 512 + f]
                         : *(const float4*)&e[(long)k * 64 + (f - 512)];
    s16x4 o; o[0] = f2bf(v.x); o[1] = f2bf(v.y); o[2] = f2bf(v.z); o[3] = f2bf(v.w);
    if (Xe) *(s16x4*)&Xe[((long)b * 2048 + k) * 576 + f] = o;
    *(s16x4*)&t[row * LP + fi] = o;
  }
  __syncthreads();
#pragma unroll
  for (int i = 0; i < 2; ++i) {
    const int c  = threadIdx.x + 256 * i;   // 0..511
    const int fr = c >> 3;                  // f row within tile
    const int kc = (c & 7) * 8;             // k chunk
    s16x8 o;
#pragma unroll
    for (int j = 0; j < 8; ++j) o[j] = t[(kc + j) * LP + fr];
    *(s16x8*)&XeT[((long)b * 576 + f0 + fr) * 2048 + k0 + kc] = o;
  }
}

// Xe only (fallback when workspace can't hold both XeT and Xe)
__global__ __launch_bounds__(256) void convert_xe(
    const float* __restrict__ x, const float* __restrict__ e,
    unsigned short* __restrict__ Xe)
{
  long g = (long)blockIdx.x * 256 + threadIdx.x;  // 16*2048*144 total
  int  c4 = (int)(g % 144);
  long bn = g / 144;
  int  n  = (int)(bn % 2048);
  int  f  = c4 * 4;
  float4 v = (f < 512) ? *(const float4*)&x[bn * 512 + f]
                       : *(const float4*)&e[(long)n * 64 + (f - 512)];
  s16x4 o; o[0] = f2bf(v.x); o[1] = f2bf(v.y); o[2] = f2bf(v.z); o[3] = f2bf(v.w);
  *(s16x4*)&Xe[bn * 576 + f] = o;
}

// ---------------------------------------------------------------------------
// Wb[m][k] (576x576 bf16) = quadrant-wise transpose of W0..W3 with
// relu(triu) on the W0 block. 32x32 LDS tiles; coalesced reads AND writes.
//  m<512,k<512 : (m>k) ? relu(W0[k][m]) : 0
//  m<512,k>=512: W1[k-512][m]
//  m>=512,k<512: W2[k][m-512]
//  m>=512,k>=512: W3[k-512][m-512]
// ---------------------------------------------------------------------------
__global__ __launch_bounds__(256) void build_wb(
    const float* __restrict__ W0, const float* __restrict__ W1,
    const float* __restrict__ W2, const float* __restrict__ W3,
    unsigned short* __restrict__ Wb)
{
  __shared__ float tw[32][33];
  const int m0 = blockIdx.x * 32;
  const int k0 = blockIdx.y * 32;
  const int r  = threadIdx.x >> 3;        // 0..31
  const int c4 = (threadIdx.x & 7) * 4;   // 0..28

  // read src[k][m] with m contiguous
  const int k = k0 + r;
  float4 v;
  if (m0 < 512) {
    if (k0 < 512) v = *(const float4*)&W0[k * 512 + m0 + c4];
    else          v = *(const float4*)&W1[(k - 512) * 512 + m0 + c4];
  } else {
    if (k0 < 512) v = *(const float4*)&W2[k * 64 + (m0 - 512) + c4];
    else          v = *(const float4*)&W3[(k - 512) * 64 + (m0 - 512) + c4];
  }
  tw[r][c4 + 0] = v.x; tw[r][c4 + 1] = v.y; tw[r][c4 + 2] = v.z; tw[r][c4 + 3] = v.w;
  __syncthreads();

  // write Wb[m][k] with k contiguous
  const int m = m0 + r;
  const bool tri = (m0 < 512) && (k0 < 512);
  s16x4 o;
#pragma unroll
  for (int j = 0; j < 4; ++j) {
    const int kk = k0 + c4 + j;
    float val = tw[c4 + j][r];
    if (tri) val = (m > kk) ? fmaxf(val, 0.f) : 0.f;
    o[j] = f2bf(val);
  }
  *(s16x4*)&Wb[m * 576 + k0 + c4] = o;
}

// ---------------------------------------------------------------------------
extern "C" void kernel_launch(void* const* d_in, const int* in_sizes, int n_in,
                              void* d_out, int out_size, void* d_ws, size_t ws_size,
                              hipStream_t stream) {
  const float* x  = (const float*)d_in[0];
  const float* e  = (const float*)d_in[1];
  const float* W0 = (const float*)d_in[2];
  const float* W1 = (const float*)d_in[3];
  const float* W2 = (const float*)d_in[4];
  const float* W3 = (const float*)d_in[5];
  float* out = (float*)d_out;

  const size_t SZ_XeT = (size_t)16 * 576 * 2048 * 2;  // 37,748,736
  const size_t SZ_CT  = (size_t)16 * 512 * 576 * 2;   //  9,437,184
  const size_t SZ_DT  = SZ_CT;
  const size_t SZ_WB  = (size_t)576 * 576 * 2;        //    663,552

  char* p = (char*)d_ws;
  unsigned short* XeT = (unsigned short*)p;  p += SZ_XeT;
  unsigned short* CT  = (unsigned short*)p;  p += SZ_CT;
  unsigned short* DT  = (unsigned short*)p;  p += SZ_DT;
  unsigned short* Wb  = (unsigned short*)p;  p += SZ_WB;
  const size_t base = SZ_XeT + SZ_CT + SZ_DT + SZ_WB;
  if (ws_size < base) return;  // insufficient workspace -> loud failure
  const bool roomy = ws_size >= base + SZ_XeT;
  unsigned short* Xe = roomy ? (unsigned short*)p : XeT;

  build_wb<<<dim3(18, 18), 256, 0, stream>>>(W0, W1, W2, W3, Wb);
  convert_fused<<<dim3(32, 9, 16), 256, 0, stream>>>(x, e, XeT,
                                                     roomy ? Xe : nullptr);

  // Stage 1: CT[i][j] = sum_k XeT[i][k]*XeT[j][k]   (M=512, N=576, K=2048)
  gemm_nt<64, 96, 8, 6, 0><<<768, 256, 0, stream>>>(
      XeT, (long)576 * 2048, 2048,
      XeT, (long)576 * 2048, 2048,
      CT,  (long)512 * 576, 576, 2048);

  if (!roomy)
    convert_xe<<<18432, 256, 0, stream>>>(x, e, Xe);

  // Stage 2: DT[t][m] = sum_f CT[t][f]*Wb[m][f]     (M=512, N=576, K=576)
  gemm_nt<64, 96, 8, 6, 0><<<768, 256, 0, stream>>>(
      CT, (long)512 * 576, 576,
      Wb, 0L, 576,
      DT, (long)512 * 576, 576, 576);

  // Stage 3: out[n][t] = sum_m Xe[n][m]*DT[t][m]    (M=2048, N=512, K=576)
  gemm_nt<128, 128, 16, 4, 1><<<1024, 256, 0, stream>>>(
      Xe, (long)2048 * 576, 576,
      DT, (long)512 * 576, 576,
      out, (long)2048 * 512, 512, 576);
}